// Round 1
// baseline (43.905 us; speedup 1.0000x reference)
//
#include <hip/hip_runtime.h>
#include <math.h>

#define B_TOTAL 2048
#define I_DIM   128
#define O_DIM   128
#define GK      68      // G + k rows in w
#define NKNOT   71      // G + 2k - 1
#define ROWSZ   (I_DIM * O_DIM)   // stride between g-rows in w: 16384 floats

// Block: 256 threads = 4 waves; each wave owns one b.
// Phase 1: 512 (b,i) pairs / block -> basis coeffs + base index into LDS.
// Phase 2: per-wave gather-accumulate, lane covers o0=2*lane (float2 loads,
//          one 512B fully-coalesced row per load instruction per wave).
__global__ __launch_bounds__(256)
void flashkan_fwd(const float* __restrict__ x,
                  const float* __restrict__ w,
                  const float* __restrict__ t,
                  float* __restrict__ out) {
    __shared__ float sh[4][I_DIM][8];   // c0..c4, g0 bits, pad to 8 (16KB)
    __shared__ float t_sh[NKNOT];

    const int tid = threadIdx.x;
    if (tid < NKNOT) t_sh[tid] = t[tid];
    __syncthreads();

    const int b0 = blockIdx.x * 4;

    // ---- Phase 1: basis per (b_local, i), 2 pairs per thread ----
    for (int pair = tid; pair < 4 * I_DIM; pair += 256) {
        const int bl = pair >> 7;
        const int ii = pair & (I_DIM - 1);
        const float xv = x[(size_t)(b0 + bl) * I_DIM + ii];

        // interval index (searchsorted 'right' - 1, clipped to [3,66])
        int ik = 3 + (int)floorf((xv + 1.0f) * 32.0f);
        ik = min(max(ik, 3), 66);
        while (ik < 66 && xv >= t_sh[ik + 1]) ++ik;
        while (ik > 3 && xv < t_sh[ik]) --ik;

        // de Boor triangular recursion, k=4 (p=3), unrolled, exact ref order
        float l0, l1, l2, r0, r1, r2;
        float N0 = 1.0f, N1, N2, N3;
        // j = 1
        l0 = xv - t_sh[ik];
        r0 = t_sh[ik + 1] - xv;
        {
            float temp = N0 / (r0 + l0);
            N0 = r0 * temp;
            N1 = l0 * temp;
        }
        // j = 2
        l1 = xv - t_sh[ik - 1];
        r1 = t_sh[ik + 2] - xv;
        {
            float saved = 0.0f, temp;
            temp = N0 / (r0 + l1);          // r=0: right[0] + left[1]
            N0 = saved + r0 * temp;
            saved = l1 * temp;
            temp = N1 / (r1 + l0);          // r=1: right[1] + left[0]
            N1 = saved + r1 * temp;
            N2 = l0 * temp;
        }
        // j = 3
        l2 = xv - t_sh[ik - 2];
        r2 = t_sh[ik + 3] - xv;
        {
            float saved = 0.0f, temp;
            temp = N0 / (r0 + l2);          // r=0: right[0] + left[2]
            N0 = saved + r0 * temp;
            saved = l2 * temp;
            temp = N1 / (r1 + l1);          // r=1: right[1] + left[1]
            N1 = saved + r1 * temp;
            saved = l1 * temp;
            temp = N2 / (r2 + l0);          // r=2: right[2] + left[0]
            N2 = saved + r2 * temp;
            N3 = l0 * temp;
        }
        const float silu = xv / (1.0f + expf(-xv));

        sh[bl][ii][0] = N0;
        sh[bl][ii][1] = N1;
        sh[bl][ii][2] = N2;
        sh[bl][ii][3] = N3;
        sh[bl][ii][4] = silu;
        sh[bl][ii][5] = __int_as_float(ik - 3);   // g0 in [0,63]
    }
    __syncthreads();

    // ---- Phase 2: gather-accumulate ----
    const int wave = tid >> 6;
    const int lane = tid & 63;
    const int b    = b0 + wave;
    const int o0   = lane * 2;

    float accx = 0.0f, accy = 0.0f;
    #pragma unroll 4
    for (int ii = 0; ii < I_DIM; ++ii) {
        const float c0 = sh[wave][ii][0];
        const float c1 = sh[wave][ii][1];
        const float c2 = sh[wave][ii][2];
        const float c3 = sh[wave][ii][3];
        const float c4 = sh[wave][ii][4];
        const int   g0 = __float_as_int(sh[wave][ii][5]);

        const float* base = w + (size_t)ii * O_DIM + o0;
        const float2 v0 = *(const float2*)(base + (size_t)(g0    ) * ROWSZ);
        const float2 v1 = *(const float2*)(base + (size_t)(g0 + 1) * ROWSZ);
        const float2 v2 = *(const float2*)(base + (size_t)(g0 + 2) * ROWSZ);
        const float2 v3 = *(const float2*)(base + (size_t)(g0 + 3) * ROWSZ);
        const float2 v4 = *(const float2*)(base + (size_t)(GK - 1) * ROWSZ);

        accx += c0 * v0.x + c1 * v1.x + c2 * v2.x + c3 * v3.x + c4 * v4.x;
        accy += c0 * v0.y + c1 * v1.y + c2 * v2.y + c3 * v3.y + c4 * v4.y;
    }

    float2 res = make_float2(accx, accy);
    *(float2*)(out + (size_t)b * O_DIM + o0) = res;
}

extern "C" void kernel_launch(void* const* d_in, const int* in_sizes, int n_in,
                              void* d_out, int out_size, void* d_ws, size_t ws_size,
                              hipStream_t stream) {
    const float* x = (const float*)d_in[0];
    const float* w = (const float*)d_in[1];
    const float* t = (const float*)d_in[2];
    float* out = (float*)d_out;

    dim3 grid(B_TOTAL / 4);
    dim3 block(256);
    flashkan_fwd<<<grid, block, 0, stream>>>(x, w, t, out);
}